// Round 1
// 1596.846 us; speedup vs baseline: 1.5990x; 1.5990x over previous
//
#include <hip/hip_runtime.h>
#include <hip/hip_bf16.h>

typedef __bf16 bf16_t;
typedef __bf16 bf16x8 __attribute__((ext_vector_type(8)));
typedef __bf16 bf16x4 __attribute__((ext_vector_type(4)));
typedef float  f32x4  __attribute__((ext_vector_type(4)));

// async global->LDS, 16B per lane. LDS dest = wave-uniform base + lane*16.
__device__ __forceinline__ void gl_lds16(const void* g, void* l) {
    __builtin_amdgcn_global_load_lds(
        (__attribute__((address_space(1))) void*)g,
        (__attribute__((address_space(3))) void*)l, 16, 0, 0);
}

// ---------------------------------------------------------------------------
// fp32 -> bf16 cast, vectorized (n must be multiple of 4)
// ---------------------------------------------------------------------------
__global__ void cvt_kernel(const float* __restrict__ in, bf16_t* __restrict__ out,
                           int n4) {
    const int i = blockIdx.x * 256 + threadIdx.x;
    if (i < n4) {
        const float4 v = ((const float4*)in)[i];
        bf16x4 o;
        o.x = (bf16_t)v.x; o.y = (bf16_t)v.y; o.z = (bf16_t)v.z; o.w = (bf16_t)v.w;
        ((bf16x4*)out)[i] = o;
    }
}

// ---------------------------------------------------------------------------
// Embedding gather: x[t,:] = wte[idx[t],:]  (fp32)
// ---------------------------------------------------------------------------
__global__ void embed_kernel(const int* __restrict__ idx,
                             const float* __restrict__ wte,
                             float* __restrict__ x) {
    const int t = blockIdx.x;
    const int row = idx[t];
    const float* w = wte + (size_t)row * 768;
    float* o = x + (size_t)t * 768;
    for (int d = threadIdx.x; d < 768; d += 256) o[d] = w[d];
}

// ---------------------------------------------------------------------------
// LayerNorm: out(bf16) = (x - mu) * rsqrt(var + eps) * w      D = 768
// ---------------------------------------------------------------------------
__global__ __launch_bounds__(256) void ln_kernel(const float* __restrict__ x,
                                                 const float* __restrict__ w,
                                                 bf16_t* __restrict__ out) {
    const int t = blockIdx.x, tid = threadIdx.x;
    __shared__ float red[256];
    const float* xr = x + (size_t)t * 768;
    const float v0 = xr[tid], v1 = xr[tid + 256], v2 = xr[tid + 512];
    red[tid] = v0 + v1 + v2;
    __syncthreads();
    for (int s = 128; s > 0; s >>= 1) {
        if (tid < s) red[tid] += red[tid + s];
        __syncthreads();
    }
    const float mu = red[0] * (1.0f / 768.0f);
    __syncthreads();
    const float d0 = v0 - mu, d1 = v1 - mu, d2 = v2 - mu;
    red[tid] = d0 * d0 + d1 * d1 + d2 * d2;
    __syncthreads();
    for (int s = 128; s > 0; s >>= 1) {
        if (tid < s) red[tid] += red[tid + s];
        __syncthreads();
    }
    const float rstd = rsqrtf(red[0] * (1.0f / 768.0f) + 1e-5f);
    bf16_t* orow = out + (size_t)t * 768;
    orow[tid]       = (bf16_t)(d0 * rstd * w[tid]);
    orow[tid + 256] = (bf16_t)(d1 * rstd * w[tid + 256]);
    orow[tid + 512] = (bf16_t)(d2 * rstd * w[tid + 512]);
}

// ---------------------------------------------------------------------------
// RoPE + bf16 pack + V transpose.
// grid (T/64, NH), block 256.
// In : qkv [T, 2304] fp32 (Q | K | V, head h at h*64)
// Out: Qb [NH][T][64] bf16 (pre-scaled by 0.125 = 1/sqrt(64))
//      Kb [NH][T][64] bf16
//      Vt [NH][64][T] bf16 (transposed so PV B-fragments are contiguous)
// ---------------------------------------------------------------------------
__global__ __launch_bounds__(256) void rope_prep(const float* __restrict__ qkv,
                                                 bf16_t* __restrict__ Qb,
                                                 bf16_t* __restrict__ Kb,
                                                 bf16_t* __restrict__ Vt) {
    const int t0 = blockIdx.x * 64, h = blockIdx.y;
    const int tid = threadIdx.x;
    __shared__ bf16_t vt[64][65];   // [d][k], padded row

    // RoPE on Q and K: 64 rows x {Q,K} x 32 freq = 4096 items, 16/thread
    #pragma unroll
    for (int it = 0; it < 16; ++it) {
        const int item = it * 256 + tid;
        const int tl = item >> 6;
        const int which = (item >> 5) & 1;   // 0 = Q, 1 = K
        const int i = item & 31;
        const float* src = qkv + (size_t)(t0 + tl) * 2304 + which * 768 + h * 64;
        const float inv_freq = __powf(10000.0f, -(float)i * (1.0f / 32.0f));
        const float ang = (float)(t0 + tl) * inv_freq;
        float s, c;
        __sincosf(ang, &s, &c);
        const float x1 = src[i], x2 = src[i + 32];
        bf16_t* dst = (which ? Kb : Qb) + ((size_t)h * 2048 + t0 + tl) * 64;
        const float sc = which ? 1.0f : 0.125f;   // fold attn scale into Q (exact pow2)
        dst[i]      = (bf16_t)((x1 * c - x2 * s) * sc);
        dst[i + 32] = (bf16_t)((x1 * s + x2 * c) * sc);
    }

    // V: load [k][d] coalesced, transpose through LDS, store [d][k] coalesced
    #pragma unroll
    for (int pass = 0; pass < 4; ++pass) {
        const int r = pass * 16 + (tid >> 4);   // key row 0..63
        const int c = (tid & 15) * 4;           // d 0..60
        const float4 v = *(const float4*)(qkv + (size_t)(t0 + r) * 2304 + 1536 + h * 64 + c);
        vt[c + 0][r] = (bf16_t)v.x;
        vt[c + 1][r] = (bf16_t)v.y;
        vt[c + 2][r] = (bf16_t)v.z;
        vt[c + 3][r] = (bf16_t)v.w;
    }
    __syncthreads();
    #pragma unroll
    for (int pass = 0; pass < 2; ++pass) {
        const int d = pass * 32 + (tid >> 3);
        const int k8 = (tid & 7) * 8;
        bf16x8 vv;
        #pragma unroll
        for (int j = 0; j < 8; ++j) vv[j] = vt[d][k8 + j];
        *(bf16x8*)(Vt + ((size_t)h * 64 + d) * 2048 + t0 + k8) = vv;
    }
}

// ---------------------------------------------------------------------------
// MFMA flash attention. Block = (64-query tile, head), 256 threads (4 waves).
// Wave w owns q rows [q0+w*16, q0+w*16+16). KV tiles of 64.
// Q pre-scaled; online softmax fully lane-parallel; P through swizzled LDS.
// LDS tiles XOR-swizzled: byte ^= ((row&7)<<4)  (row-major [64][128B] would be
// a 16-way bank conflict on ds_read_b128 otherwise).
// ---------------------------------------------------------------------------
__global__ __launch_bounds__(256) void attn_mfma(const bf16_t* __restrict__ Qb,
                                                 const bf16_t* __restrict__ Kb,
                                                 const bf16_t* __restrict__ Vt,
                                                 bf16_t* __restrict__ y) {
    const int qt = (int)gridDim.x - 1 - (int)blockIdx.x;  // longest blocks first
    const int h  = blockIdx.y;
    const int q0 = qt * 64;
    const int tid = threadIdx.x;
    const int w = tid >> 6, lane = tid & 63;
    const int lg = lane >> 4;       // lane group 0..3
    const int ll = lane & 15;

    __shared__ bf16_t Ks[64 * 64];  // [key][d], swizzled
    __shared__ bf16_t Vs[64 * 64];  // [d][key] (V^T tile), swizzled
    __shared__ bf16_t Ps[64 * 64];  // [q][key], swizzled (per-wave private rows)

    // Q A-fragments: row = q0 + w*16 + ll, k(d) = lg*8 (+32 for 2nd K-half)
    bf16x8 aq0, aq1;
    {
        const bf16_t* qp = Qb + ((size_t)h * 2048 + q0 + w * 16 + ll) * 64 + lg * 8;
        aq0 = *(const bf16x8*)qp;
        aq1 = *(const bf16x8*)(qp + 32);
    }

    f32x4 o[4];
    #pragma unroll
    for (int i = 0; i < 4; ++i) o[i] = (f32x4)(0.0f);
    float m_i[4], l_i[4];
    #pragma unroll
    for (int r = 0; r < 4; ++r) { m_i[r] = -3e38f; l_i[r] = 0.0f; }

    // staging map: 512 chunks of 16B per 8KB tile, 2 per thread
    const int srow0 = tid >> 3;          // rows 0..31
    const int srow1 = srow0 + 32;        // rows 32..63
    const int sc16  = tid & 7;           // 16B chunk within 128B row

    const bf16_t* Kbase = Kb + (size_t)h * 2048 * 64;
    const bf16_t* Vbase = Vt + (size_t)h * 64 * 2048;

    for (int kt = 0; kt <= qt; ++kt) {
        __syncthreads();   // previous tile fully consumed
        {
            const bf16_t* kg = Kbase + (size_t)(kt * 64) * 64;
            const bf16x8 k0 = *(const bf16x8*)(kg + srow0 * 64 + sc16 * 8);
            const bf16x8 k1 = *(const bf16x8*)(kg + srow1 * 64 + sc16 * 8);
            const bf16_t* vg = Vbase + kt * 64;
            const bf16x8 v0 = *(const bf16x8*)(vg + (size_t)srow0 * 2048 + sc16 * 8);
            const bf16x8 v1 = *(const bf16x8*)(vg + (size_t)srow1 * 2048 + sc16 * 8);
            *(bf16x8*)((char*)(Ks + srow0 * 64) + ((sc16 * 16) ^ ((srow0 & 7) << 4))) = k0;
            *(bf16x8*)((char*)(Ks + srow1 * 64) + ((sc16 * 16) ^ ((srow1 & 7) << 4))) = k1;
            *(bf16x8*)((char*)(Vs + srow0 * 64) + ((sc16 * 16) ^ ((srow0 & 7) << 4))) = v0;
            *(bf16x8*)((char*)(Vs + srow1 * 64) + ((sc16 * 16) ^ ((srow1 & 7) << 4))) = v1;
        }
        __syncthreads();

        // ---- S = (Q*0.125) @ K^T : 16q x 64k per wave, 8 MFMAs ----
        f32x4 sacc[4];
        #pragma unroll
        for (int kb = 0; kb < 4; ++kb) {
            const int krow = kb * 16 + ll;
            const char* kr = (const char*)(Ks + krow * 64);
            const int sw = (krow & 7) << 4;
            const bf16x8 b0 = *(const bf16x8*)(kr + ((lg * 16) ^ sw));
            const bf16x8 b1 = *(const bf16x8*)(kr + ((64 + lg * 16) ^ sw));
            sacc[kb] = __builtin_amdgcn_mfma_f32_16x16x32_bf16(aq0, b0, (f32x4)(0.0f), 0, 0, 0);
            sacc[kb] = __builtin_amdgcn_mfma_f32_16x16x32_bf16(aq1, b1, sacc[kb], 0, 0, 0);
        }

        // ---- causal mask + online softmax (C layout: col=ll, row=lg*4+r) ----
        float sc_[4][4];
        const bool diag = (kt == qt);
        #pragma unroll
        for (int kb = 0; kb < 4; ++kb) {
            #pragma unroll
            for (int r = 0; r < 4; ++r) {
                float v = sacc[kb][r];
                if (diag && (kb * 16 + ll) > (w * 16 + lg * 4 + r)) v = -3e38f;
                sc_[kb][r] = v;
            }
        }
        float rmax[4];
        #pragma unroll
        for (int r = 0; r < 4; ++r)
            rmax[r] = fmaxf(fmaxf(sc_[0][r], sc_[1][r]), fmaxf(sc_[2][r], sc_[3][r]));
        #pragma unroll
        for (int st = 0; st < 4; ++st) {
            const int off = 1 << st;    // row spread over 16 lanes (low 4 bits)
            #pragma unroll
            for (int r = 0; r < 4; ++r)
                rmax[r] = fmaxf(rmax[r], __shfl_xor(rmax[r], off));
        }
        float alpha[4], rsum[4];
        #pragma unroll
        for (int r = 0; r < 4; ++r) {
            const float mn = fmaxf(m_i[r], rmax[r]);
            alpha[r] = __expf(m_i[r] - mn);
            m_i[r] = mn;
            rsum[r] = 0.0f;
        }
        #pragma unroll
        for (int kb = 0; kb < 4; ++kb) {
            #pragma unroll
            for (int r = 0; r < 4; ++r) {
                const float p = __expf(sc_[kb][r] - m_i[r]);
                sc_[kb][r] = p;
                rsum[r] += p;
            }
        }
        #pragma unroll
        for (int st = 0; st < 4; ++st) {
            const int off = 1 << st;
            #pragma unroll
            for (int r = 0; r < 4; ++r)
                rsum[r] += __shfl_xor(rsum[r], off);
        }
        #pragma unroll
        for (int r = 0; r < 4; ++r) l_i[r] = l_i[r] * alpha[r] + rsum[r];

        // ---- P -> LDS (bf16, swizzled); rows are wave-private ----
        #pragma unroll
        for (int r = 0; r < 4; ++r) {
            const int prow = w * 16 + lg * 4 + r;
            char* pb = (char*)(Ps + prow * 64);
            const int sw = (prow & 7) << 4;
            #pragma unroll
            for (int kb = 0; kb < 4; ++kb)
                *(bf16_t*)(pb + (((kb * 16 + ll) * 2) ^ sw)) = (bf16_t)sc_[kb][r];
        }

        // ---- rescale O, then O += P @ V : 8 MFMAs ----
        #pragma unroll
        for (int db = 0; db < 4; ++db)
            #pragma unroll
            for (int r = 0; r < 4; ++r) o[db][r] *= alpha[r];

        #pragma unroll
        for (int ks = 0; ks < 2; ++ks) {
            const int arow = w * 16 + ll;
            const bf16x8 ap = *(const bf16x8*)((const char*)(Ps + arow * 64) +
                                ((ks * 64 + lg * 16) ^ ((arow & 7) << 4)));
            #pragma unroll
            for (int db = 0; db < 4; ++db) {
                const int vrow = db * 16 + ll;
                const bf16x8 bv = *(const bf16x8*)((const char*)(Vs + vrow * 64) +
                                    ((ks * 64 + lg * 16) ^ ((vrow & 7) << 4)));
                o[db] = __builtin_amdgcn_mfma_f32_16x16x32_bf16(ap, bv, o[db], 0, 0, 0);
            }
        }
    }

    // epilogue: y[q][h*64 + d] = O / l
    #pragma unroll
    for (int r = 0; r < 4; ++r) {
        const float inv = 1.0f / l_i[r];
        bf16_t* yo = y + (size_t)(q0 + w * 16 + lg * 4 + r) * 768 + h * 64 + ll;
        #pragma unroll
        for (int db = 0; db < 4; ++db)
            yo[db * 16] = (bf16_t)(o[db][r] * inv);
    }
}

// ---------------------------------------------------------------------------
// MFMA NT GEMM: C[M,N] = A[M,K](bf16) * B[N,K](bf16)^T, fp32 accumulate.
// Tile 128x128, BK=32, 256 threads (4 waves, 2x2 of 64x64).
// Staging via global_load_lds width=16. M,N % 128 == 0, K % 32 == 0.
// FLAGS: 1=bias(fp32), 2=residual into C32, 4=exact GELU, 8=bf16 out
// ---------------------------------------------------------------------------
template <int FLAGS>
__global__ __launch_bounds__(256) void gemm_bt(const bf16_t* __restrict__ A,
                                               const bf16_t* __restrict__ B,
                                               const float* __restrict__ bias,
                                               float* __restrict__ C32,
                                               bf16_t* __restrict__ Cb,
                                               int M, int N, int K) {
    constexpr bool HAS_BIAS = (FLAGS & 1) != 0;
    constexpr bool HAS_RES  = (FLAGS & 2) != 0;
    constexpr bool HAS_GELU = (FLAGS & 4) != 0;
    constexpr bool OUT_BF16 = (FLAGS & 8) != 0;

    __shared__ bf16_t As[128 * 32];
    __shared__ bf16_t Bs[128 * 32];

    const int tid = threadIdx.x;
    const int w = tid >> 6, lane = tid & 63;
    const int bm = blockIdx.y * 128, bn = blockIdx.x * 128;
    const int wm = (w >> 1) * 64, wn = (w & 1) * 64;

    const int sr = w * 32 + (lane >> 2);
    const int sc = (lane & 3) * 8;
    const bf16_t* gA0 = A + (size_t)(bm + sr) * K + sc;
    const bf16_t* gA1 = gA0 + (size_t)16 * K;
    const bf16_t* gB0 = B + (size_t)(bn + sr) * K + sc;
    const bf16_t* gB1 = gB0 + (size_t)16 * K;
    bf16_t* lA0 = As + (w * 32) * 32;
    bf16_t* lA1 = As + (w * 32 + 16) * 32;
    bf16_t* lB0 = Bs + (w * 32) * 32;
    bf16_t* lB1 = Bs + (w * 32 + 16) * 32;

    const int mrow  = lane & 15;
    const int khalf = (lane >> 4) * 8;

    f32x4 acc[4][4];
    #pragma unroll
    for (int i = 0; i < 4; ++i)
        #pragma unroll
        for (int j = 0; j < 4; ++j) acc[i][j] = (f32x4)(0.0f);

    for (int k0 = 0; k0 < K; k0 += 32) {
        __syncthreads();
        gl_lds16(gA0 + k0, lA0);
        gl_lds16(gA1 + k0, lA1);
        gl_lds16(gB0 + k0, lB0);
        gl_lds16(gB1 + k0, lB1);
        __syncthreads();
        bf16x8 af[4], bfr[4];
        #pragma unroll
        for (int i = 0; i < 4; ++i)
            af[i] = *(const bf16x8*)(As + (wm + i * 16 + mrow) * 32 + khalf);
        #pragma unroll
        for (int j = 0; j < 4; ++j)
            bfr[j] = *(const bf16x8*)(Bs + (wn + j * 16 + mrow) * 32 + khalf);
        #pragma unroll
        for (int i = 0; i < 4; ++i)
            #pragma unroll
            for (int j = 0; j < 4; ++j)
                acc[i][j] = __builtin_amdgcn_mfma_f32_16x16x32_bf16(
                    af[i], bfr[j], acc[i][j], 0, 0, 0);
    }

    const int ccol = lane & 15;
    const int crow = (lane >> 4) * 4;
    #pragma unroll
    for (int i = 0; i < 4; ++i) {
        #pragma unroll
        for (int j = 0; j < 4; ++j) {
            const int col = bn + wn + j * 16 + ccol;
            #pragma unroll
            for (int r = 0; r < 4; ++r) {
                const int row = bm + wm + i * 16 + crow + r;
                float v = acc[i][j][r];
                if constexpr (HAS_BIAS) v += bias[col];
                if constexpr (HAS_GELU) v = 0.5f * v * (1.0f + erff(v * 0.70710678f));
                const size_t off = (size_t)row * N + col;
                if constexpr (HAS_RES) v += C32[off];
                if constexpr (OUT_BF16) Cb[off] = (bf16_t)v;
                else C32[off] = v;
            }
        }
    }
}

// ---------------------------------------------------------------------------
// Host launch
// ---------------------------------------------------------------------------
extern "C" void kernel_launch(void* const* d_in, const int* in_sizes, int n_in,
                              void* d_out, int out_size, void* d_ws, size_t ws_size,
                              hipStream_t stream) {
    const int T = 2048, D = 768, NH = 12, L = 4, V = 32000;
    const int D3 = 3 * D, D4 = 4 * D;

    const int*   idx        = (const int*)d_in[0];
    const float* wte        = (const float*)d_in[1];
    const float* ln1_w      = (const float*)d_in[2];
    const float* attn_w     = (const float*)d_in[3];
    const float* attnproj_w = (const float*)d_in[4];
    const float* ln2_w      = (const float*)d_in[5];
    const float* fc_w       = (const float*)d_in[6];
    const float* fc_b       = (const float*)d_in[7];
    const float* proj_w     = (const float*)d_in[8];
    const float* proj_b     = (const float*)d_in[9];
    const float* lnf_w      = (const float*)d_in[10];
    const float* unemb_b    = (const float*)d_in[11];
    float* out = (float*)d_out;

    // workspace layout (~91.6 MB)
    char* p = (char*)d_ws;
    float*  X      = (float*)p;   p += (size_t)T * D * 4;        // 6.29 MB
    bf16_t* Hb     = (bf16_t*)p;  p += (size_t)T * D * 2;        // 3.15 MB
    float*  QKV    = (float*)p;                                   // 18.9 MB
    bf16_t* Mb     = (bf16_t*)p;  p += (size_t)T * D3 * 4;       // (union, QKV larger)
    bf16_t* wte_b  = (bf16_t*)p;  p += (size_t)V * D * 2;        // 49.2 MB
    bf16_t* w_attn = (bf16_t*)p;  p += (size_t)D3 * D * 2;
    bf16_t* w_apr  = (bf16_t*)p;  p += (size_t)D * D * 2;
    bf16_t* w_fc   = (bf16_t*)p;  p += (size_t)D4 * D * 2;
    bf16_t* w_proj = (bf16_t*)p;  p += (size_t)D * D4 * 2;

    // Q/K/V^T bf16 buffers overlay wte_b (dead until after the layer loop;
    // wte cast is deferred to just before the unembedding GEMM).
    bf16_t* Qb  = wte_b;
    bf16_t* Kbf = Qb  + (size_t)NH * T * 64;    // 3.15 MB each
    bf16_t* Vtg = Kbf + (size_t)NH * T * 64;

    embed_kernel<<<T, 256, 0, stream>>>(idx, wte, X);

    for (int l = 0; l < L; ++l) {
        // per-layer weight casts (fp32 -> bf16)
        int n4;
        n4 = D3 * D / 4;
        cvt_kernel<<<(n4 + 255) / 256, 256, 0, stream>>>(attn_w + (size_t)l * D3 * D, w_attn, n4);
        n4 = D * D / 4;
        cvt_kernel<<<(n4 + 255) / 256, 256, 0, stream>>>(attnproj_w + (size_t)l * D * D, w_apr, n4);
        n4 = D4 * D / 4;
        cvt_kernel<<<(n4 + 255) / 256, 256, 0, stream>>>(fc_w + (size_t)l * D4 * D, w_fc, n4);
        n4 = D * D4 / 4;
        cvt_kernel<<<(n4 + 255) / 256, 256, 0, stream>>>(proj_w + (size_t)l * D * D4, w_proj, n4);

        // h = LN1(x)  (bf16)
        ln_kernel<<<T, 256, 0, stream>>>(X, ln1_w + (size_t)l * D, Hb);
        // qkv = h @ attn_w^T  (fp32 out)
        gemm_bt<0><<<dim3(D3 / 128, T / 128), 256, 0, stream>>>(
            Hb, w_attn, nullptr, QKV, nullptr, T, D3, D);
        // RoPE + bf16 pack + V transpose
        rope_prep<<<dim3(T / 64, NH), 256, 0, stream>>>(QKV, Qb, Kbf, Vtg);
        // y = attn(q,k,v)  (bf16 into Hb)
        attn_mfma<<<dim3(T / 64, NH), 256, 0, stream>>>(Qb, Kbf, Vtg, Hb);
        // x += y @ attnproj_w^T
        gemm_bt<2><<<dim3(D / 128, T / 128), 256, 0, stream>>>(
            Hb, w_apr, nullptr, X, nullptr, T, D, D);
        // h = LN2(x)
        ln_kernel<<<T, 256, 0, stream>>>(X, ln2_w + (size_t)l * D, Hb);
        // m = gelu(h @ fc_w^T + fc_b)  (bf16 out)
        gemm_bt<13><<<dim3(D4 / 128, T / 128), 256, 0, stream>>>(
            Hb, w_fc, fc_b + (size_t)l * D4, nullptr, Mb, T, D4, D);
        // x += m @ proj_w^T + proj_b
        gemm_bt<3><<<dim3(D / 128, T / 128), 256, 0, stream>>>(
            Mb, w_proj, proj_b + (size_t)l * D, X, nullptr, T, D, D4);
    }

    // hf = LN(x); logits = hf @ wte^T + unemb_b  (fp32 out)
    ln_kernel<<<T, 256, 0, stream>>>(X, lnf_w, Hb);
    {
        const int n4 = V * D / 4;   // deferred: wte_b region was reused above
        cvt_kernel<<<(n4 + 255) / 256, 256, 0, stream>>>(wte, wte_b, n4);
    }
    gemm_bt<1><<<dim3(V / 128, T / 128), 256, 0, stream>>>(
        Hb, wte_b, unemb_b, out, nullptr, T, V, D);
}

// Round 2
// 1422.694 us; speedup vs baseline: 1.7948x; 1.1224x over previous
//
#include <hip/hip_runtime.h>
#include <hip/hip_bf16.h>

typedef __bf16 bf16_t;
typedef __bf16 bf16x8 __attribute__((ext_vector_type(8)));
typedef __bf16 bf16x4 __attribute__((ext_vector_type(4)));
typedef float  f32x4  __attribute__((ext_vector_type(4)));

// async global->LDS, 16B per lane. LDS dest = wave-uniform base + lane*16.
__device__ __forceinline__ void gl_lds16(const void* g, void* l) {
    __builtin_amdgcn_global_load_lds(
        (__attribute__((address_space(1))) void*)g,
        (__attribute__((address_space(3))) void*)l, 16, 0, 0);
}

// ---------------------------------------------------------------------------
// fp32 -> bf16 cast, vectorized (n must be multiple of 4)
// ---------------------------------------------------------------------------
__global__ void cvt_kernel(const float* __restrict__ in, bf16_t* __restrict__ out,
                           int n4) {
    const int i = blockIdx.x * 256 + threadIdx.x;
    if (i < n4) {
        const float4 v = ((const float4*)in)[i];
        bf16x4 o;
        o.x = (bf16_t)v.x; o.y = (bf16_t)v.y; o.z = (bf16_t)v.z; o.w = (bf16_t)v.w;
        ((bf16x4*)out)[i] = o;
    }
}

// ---------------------------------------------------------------------------
// Embedding gather: x[t,:] = wte[idx[t],:]  (fp32)
// ---------------------------------------------------------------------------
__global__ void embed_kernel(const int* __restrict__ idx,
                             const float* __restrict__ wte,
                             float* __restrict__ x) {
    const int t = blockIdx.x;
    const int row = idx[t];
    const float* w = wte + (size_t)row * 768;
    float* o = x + (size_t)t * 768;
    for (int d = threadIdx.x; d < 768; d += 256) o[d] = w[d];
}

// ---------------------------------------------------------------------------
// LayerNorm: out(bf16) = (x - mu) * rsqrt(var + eps) * w      D = 768
// ---------------------------------------------------------------------------
__global__ __launch_bounds__(256) void ln_kernel(const float* __restrict__ x,
                                                 const float* __restrict__ w,
                                                 bf16_t* __restrict__ out) {
    const int t = blockIdx.x, tid = threadIdx.x;
    __shared__ float red[256];
    const float* xr = x + (size_t)t * 768;
    const float v0 = xr[tid], v1 = xr[tid + 256], v2 = xr[tid + 512];
    red[tid] = v0 + v1 + v2;
    __syncthreads();
    for (int s = 128; s > 0; s >>= 1) {
        if (tid < s) red[tid] += red[tid + s];
        __syncthreads();
    }
    const float mu = red[0] * (1.0f / 768.0f);
    __syncthreads();
    const float d0 = v0 - mu, d1 = v1 - mu, d2 = v2 - mu;
    red[tid] = d0 * d0 + d1 * d1 + d2 * d2;
    __syncthreads();
    for (int s = 128; s > 0; s >>= 1) {
        if (tid < s) red[tid] += red[tid + s];
        __syncthreads();
    }
    const float rstd = rsqrtf(red[0] * (1.0f / 768.0f) + 1e-5f);
    bf16_t* orow = out + (size_t)t * 768;
    orow[tid]       = (bf16_t)(d0 * rstd * w[tid]);
    orow[tid + 256] = (bf16_t)(d1 * rstd * w[tid + 256]);
    orow[tid + 512] = (bf16_t)(d2 * rstd * w[tid + 512]);
}

// ---------------------------------------------------------------------------
// RoPE + bf16 pack + V transpose.
// grid (T/64, NH), block 256.
// ---------------------------------------------------------------------------
__global__ __launch_bounds__(256) void rope_prep(const float* __restrict__ qkv,
                                                 bf16_t* __restrict__ Qb,
                                                 bf16_t* __restrict__ Kb,
                                                 bf16_t* __restrict__ Vt) {
    const int t0 = blockIdx.x * 64, h = blockIdx.y;
    const int tid = threadIdx.x;
    __shared__ bf16_t vt[64][65];   // [d][k], padded row

    #pragma unroll
    for (int it = 0; it < 16; ++it) {
        const int item = it * 256 + tid;
        const int tl = item >> 6;
        const int which = (item >> 5) & 1;   // 0 = Q, 1 = K
        const int i = item & 31;
        const float* src = qkv + (size_t)(t0 + tl) * 2304 + which * 768 + h * 64;
        const float inv_freq = __powf(10000.0f, -(float)i * (1.0f / 32.0f));
        const float ang = (float)(t0 + tl) * inv_freq;
        float s, c;
        __sincosf(ang, &s, &c);
        const float x1 = src[i], x2 = src[i + 32];
        bf16_t* dst = (which ? Kb : Qb) + ((size_t)h * 2048 + t0 + tl) * 64;
        const float sc = which ? 1.0f : 0.125f;   // fold attn scale into Q
        dst[i]      = (bf16_t)((x1 * c - x2 * s) * sc);
        dst[i + 32] = (bf16_t)((x1 * s + x2 * c) * sc);
    }

    #pragma unroll
    for (int pass = 0; pass < 4; ++pass) {
        const int r = pass * 16 + (tid >> 4);   // key row 0..63
        const int c = (tid & 15) * 4;           // d 0..60
        const float4 v = *(const float4*)(qkv + (size_t)(t0 + r) * 2304 + 1536 + h * 64 + c);
        vt[c + 0][r] = (bf16_t)v.x;
        vt[c + 1][r] = (bf16_t)v.y;
        vt[c + 2][r] = (bf16_t)v.z;
        vt[c + 3][r] = (bf16_t)v.w;
    }
    __syncthreads();
    #pragma unroll
    for (int pass = 0; pass < 2; ++pass) {
        const int d = pass * 32 + (tid >> 3);
        const int k8 = (tid & 7) * 8;
        bf16x8 vv;
        #pragma unroll
        for (int j = 0; j < 8; ++j) vv[j] = vt[d][k8 + j];
        *(bf16x8*)(Vt + ((size_t)h * 64 + d) * 2048 + t0 + k8) = vv;
    }
}

// ---------------------------------------------------------------------------
// MFMA flash attention. Block = (64-query tile, head), 256 threads (4 waves).
// ---------------------------------------------------------------------------
__global__ __launch_bounds__(256) void attn_mfma(const bf16_t* __restrict__ Qb,
                                                 const bf16_t* __restrict__ Kb,
                                                 const bf16_t* __restrict__ Vt,
                                                 bf16_t* __restrict__ y) {
    const int qt = (int)gridDim.x - 1 - (int)blockIdx.x;  // longest blocks first
    const int h  = blockIdx.y;
    const int q0 = qt * 64;
    const int tid = threadIdx.x;
    const int w = tid >> 6, lane = tid & 63;
    const int lg = lane >> 4;       // lane group 0..3
    const int ll = lane & 15;

    __shared__ bf16_t Ks[64 * 64];  // [key][d], swizzled
    __shared__ bf16_t Vs[64 * 64];  // [d][key] (V^T tile), swizzled
    __shared__ bf16_t Ps[64 * 64];  // [q][key], swizzled (per-wave private rows)

    bf16x8 aq0, aq1;
    {
        const bf16_t* qp = Qb + ((size_t)h * 2048 + q0 + w * 16 + ll) * 64 + lg * 8;
        aq0 = *(const bf16x8*)qp;
        aq1 = *(const bf16x8*)(qp + 32);
    }

    f32x4 o[4];
    #pragma unroll
    for (int i = 0; i < 4; ++i) o[i] = (f32x4)(0.0f);
    float m_i[4], l_i[4];
    #pragma unroll
    for (int r = 0; r < 4; ++r) { m_i[r] = -3e38f; l_i[r] = 0.0f; }

    const int srow0 = tid >> 3;          // rows 0..31
    const int srow1 = srow0 + 32;        // rows 32..63
    const int sc16  = tid & 7;           // 16B chunk within 128B row

    const bf16_t* Kbase = Kb + (size_t)h * 2048 * 64;
    const bf16_t* Vbase = Vt + (size_t)h * 64 * 2048;

    for (int kt = 0; kt <= qt; ++kt) {
        __syncthreads();
        {
            const bf16_t* kg = Kbase + (size_t)(kt * 64) * 64;
            const bf16x8 k0 = *(const bf16x8*)(kg + srow0 * 64 + sc16 * 8);
            const bf16x8 k1 = *(const bf16x8*)(kg + srow1 * 64 + sc16 * 8);
            const bf16_t* vg = Vbase + kt * 64;
            const bf16x8 v0 = *(const bf16x8*)(vg + (size_t)srow0 * 2048 + sc16 * 8);
            const bf16x8 v1 = *(const bf16x8*)(vg + (size_t)srow1 * 2048 + sc16 * 8);
            *(bf16x8*)((char*)(Ks + srow0 * 64) + ((sc16 * 16) ^ ((srow0 & 7) << 4))) = k0;
            *(bf16x8*)((char*)(Ks + srow1 * 64) + ((sc16 * 16) ^ ((srow1 & 7) << 4))) = k1;
            *(bf16x8*)((char*)(Vs + srow0 * 64) + ((sc16 * 16) ^ ((srow0 & 7) << 4))) = v0;
            *(bf16x8*)((char*)(Vs + srow1 * 64) + ((sc16 * 16) ^ ((srow1 & 7) << 4))) = v1;
        }
        __syncthreads();

        // ---- S = (Q*0.125) @ K^T ----
        f32x4 sacc[4];
        #pragma unroll
        for (int kb = 0; kb < 4; ++kb) {
            const int krow = kb * 16 + ll;
            const char* kr = (const char*)(Ks + krow * 64);
            const int sw = (krow & 7) << 4;
            const bf16x8 b0 = *(const bf16x8*)(kr + ((lg * 16) ^ sw));
            const bf16x8 b1 = *(const bf16x8*)(kr + ((64 + lg * 16) ^ sw));
            sacc[kb] = __builtin_amdgcn_mfma_f32_16x16x32_bf16(aq0, b0, (f32x4)(0.0f), 0, 0, 0);
            sacc[kb] = __builtin_amdgcn_mfma_f32_16x16x32_bf16(aq1, b1, sacc[kb], 0, 0, 0);
        }

        // ---- causal mask + online softmax ----
        float sc_[4][4];
        const bool diag = (kt == qt);
        #pragma unroll
        for (int kb = 0; kb < 4; ++kb) {
            #pragma unroll
            for (int r = 0; r < 4; ++r) {
                float v = sacc[kb][r];
                if (diag && (kb * 16 + ll) > (w * 16 + lg * 4 + r)) v = -3e38f;
                sc_[kb][r] = v;
            }
        }
        float rmax[4];
        #pragma unroll
        for (int r = 0; r < 4; ++r)
            rmax[r] = fmaxf(fmaxf(sc_[0][r], sc_[1][r]), fmaxf(sc_[2][r], sc_[3][r]));
        #pragma unroll
        for (int st = 0; st < 4; ++st) {
            const int off = 1 << st;
            #pragma unroll
            for (int r = 0; r < 4; ++r)
                rmax[r] = fmaxf(rmax[r], __shfl_xor(rmax[r], off));
        }
        float alpha[4], rsum[4];
        #pragma unroll
        for (int r = 0; r < 4; ++r) {
            const float mn = fmaxf(m_i[r], rmax[r]);
            alpha[r] = __expf(m_i[r] - mn);
            m_i[r] = mn;
            rsum[r] = 0.0f;
        }
        #pragma unroll
        for (int kb = 0; kb < 4; ++kb) {
            #pragma unroll
            for (int r = 0; r < 4; ++r) {
                const float p = __expf(sc_[kb][r] - m_i[r]);
                sc_[kb][r] = p;
                rsum[r] += p;
            }
        }
        #pragma unroll
        for (int st = 0; st < 4; ++st) {
            const int off = 1 << st;
            #pragma unroll
            for (int r = 0; r < 4; ++r)
                rsum[r] += __shfl_xor(rsum[r], off);
        }
        #pragma unroll
        for (int r = 0; r < 4; ++r) l_i[r] = l_i[r] * alpha[r] + rsum[r];

        // ---- P -> LDS (bf16, swizzled) ----
        #pragma unroll
        for (int r = 0; r < 4; ++r) {
            const int prow = w * 16 + lg * 4 + r;
            char* pb = (char*)(Ps + prow * 64);
            const int sw = (prow & 7) << 4;
            #pragma unroll
            for (int kb = 0; kb < 4; ++kb)
                *(bf16_t*)(pb + (((kb * 16 + ll) * 2) ^ sw)) = (bf16_t)sc_[kb][r];
        }

        // ---- rescale O, then O += P @ V ----
        #pragma unroll
        for (int db = 0; db < 4; ++db)
            #pragma unroll
            for (int r = 0; r < 4; ++r) o[db][r] *= alpha[r];

        #pragma unroll
        for (int ks = 0; ks < 2; ++ks) {
            const int arow = w * 16 + ll;
            const bf16x8 ap = *(const bf16x8*)((const char*)(Ps + arow * 64) +
                                ((ks * 64 + lg * 16) ^ ((arow & 7) << 4)));
            #pragma unroll
            for (int db = 0; db < 4; ++db) {
                const int vrow = db * 16 + ll;
                const bf16x8 bv = *(const bf16x8*)((const char*)(Vs + vrow * 64) +
                                    ((ks * 64 + lg * 16) ^ ((vrow & 7) << 4)));
                o[db] = __builtin_amdgcn_mfma_f32_16x16x32_bf16(ap, bv, o[db], 0, 0, 0);
            }
        }
    }

    #pragma unroll
    for (int r = 0; r < 4; ++r) {
        const float inv = 1.0f / l_i[r];
        bf16_t* yo = y + (size_t)(q0 + w * 16 + lg * 4 + r) * 768 + h * 64 + ll;
        #pragma unroll
        for (int db = 0; db < 4; ++db)
            yo[db * 16] = (bf16_t)(o[db][r] * inv);
    }
}

// ---------------------------------------------------------------------------
// MFMA NT GEMM: C[M,N] = A[M,K](bf16) * B[N,K](bf16)^T, fp32 accumulate.
// Tile BM x 128 (BM in {128, 64}), BK=32, 256 threads (4 waves).
// FLAGS: 1=bias(fp32), 2=residual into C32, 4=exact GELU, 8=bf16 out,
//        16=unembed mode (swap grid axes for B-panel reuse + nontemporal C)
// ---------------------------------------------------------------------------
template <int FLAGS, int BM>
__global__ __launch_bounds__(256) void gemm_bt(const bf16_t* __restrict__ A,
                                               const bf16_t* __restrict__ B,
                                               const float* __restrict__ bias,
                                               float* __restrict__ C32,
                                               bf16_t* __restrict__ Cb,
                                               int M, int N, int K) {
    constexpr bool HAS_BIAS = (FLAGS & 1) != 0;
    constexpr bool HAS_RES  = (FLAGS & 2) != 0;
    constexpr bool HAS_GELU = (FLAGS & 4) != 0;
    constexpr bool OUT_BF16 = (FLAGS & 8) != 0;
    constexpr bool UNEMB    = (FLAGS & 16) != 0;
    constexpr int  WM       = (BM == 128) ? 64 : 32;   // wave M extent
    constexpr int  MI       = WM / 16;                 // M fragments per wave

    __shared__ bf16_t As[BM * 32];
    __shared__ bf16_t Bs[128 * 32];

    const int tid = threadIdx.x;
    const int w = tid >> 6, lane = tid & 63;
    const int bm = (UNEMB ? blockIdx.x : blockIdx.y) * BM;
    const int bn = (UNEMB ? blockIdx.y : blockIdx.x) * 128;
    const int wm = (w >> 1) * WM, wn = (w & 1) * 64;

    const int sc = (lane & 3) * 8;
    // B staging: wave w covers B rows [w*32, w*32+32)
    const int srB = w * 32 + (lane >> 2);
    const bf16_t* gB0 = B + (size_t)(bn + srB) * K + sc;
    const bf16_t* gB1 = gB0 + (size_t)16 * K;
    bf16_t* lB0 = Bs + (w * 32) * 32;
    bf16_t* lB1 = lB0 + 16 * 32;
    // A staging: BM=128 -> 32 rows/wave (2 chunks); BM=64 -> 16 rows/wave (1)
    const int srA = (BM == 128) ? srB : (w * 16 + (lane >> 2));
    const bf16_t* gA0 = A + (size_t)(bm + srA) * K + sc;
    const bf16_t* gA1 = gA0 + (size_t)16 * K;
    bf16_t* lA0 = As + ((BM == 128) ? (w * 32) * 32 : (w * 16) * 32);
    bf16_t* lA1 = lA0 + 16 * 32;

    const int mrow  = lane & 15;
    const int khalf = (lane >> 4) * 8;

    f32x4 acc[MI][4];
    #pragma unroll
    for (int i = 0; i < MI; ++i)
        #pragma unroll
        for (int j = 0; j < 4; ++j) acc[i][j] = (f32x4)(0.0f);

    for (int k0 = 0; k0 < K; k0 += 32) {
        __syncthreads();
        gl_lds16(gA0 + k0, lA0);
        if constexpr (BM == 128) gl_lds16(gA1 + k0, lA1);
        gl_lds16(gB0 + k0, lB0);
        gl_lds16(gB1 + k0, lB1);
        __syncthreads();
        bf16x8 af[MI], bfr[4];
        #pragma unroll
        for (int i = 0; i < MI; ++i)
            af[i] = *(const bf16x8*)(As + (wm + i * 16 + mrow) * 32 + khalf);
        #pragma unroll
        for (int j = 0; j < 4; ++j)
            bfr[j] = *(const bf16x8*)(Bs + (wn + j * 16 + mrow) * 32 + khalf);
        #pragma unroll
        for (int i = 0; i < MI; ++i)
            #pragma unroll
            for (int j = 0; j < 4; ++j)
                acc[i][j] = __builtin_amdgcn_mfma_f32_16x16x32_bf16(
                    af[i], bfr[j], acc[i][j], 0, 0, 0);
    }

    const int ccol = lane & 15;
    const int crow = (lane >> 4) * 4;
    #pragma unroll
    for (int i = 0; i < MI; ++i) {
        #pragma unroll
        for (int j = 0; j < 4; ++j) {
            const int col = bn + wn + j * 16 + ccol;
            #pragma unroll
            for (int r = 0; r < 4; ++r) {
                const int row = bm + wm + i * 16 + crow + r;
                float v = acc[i][j][r];
                if constexpr (HAS_BIAS) v += bias[col];
                if constexpr (HAS_GELU) v = 0.5f * v * (1.0f + erff(v * 0.70710678f));
                const size_t off = (size_t)row * N + col;
                if constexpr (HAS_RES) v += C32[off];
                if constexpr (OUT_BF16) Cb[off] = (bf16_t)v;
                else if constexpr (UNEMB) __builtin_nontemporal_store(v, &C32[off]);
                else C32[off] = v;
            }
        }
    }
}

// ---------------------------------------------------------------------------
// Host launch
// ---------------------------------------------------------------------------
extern "C" void kernel_launch(void* const* d_in, const int* in_sizes, int n_in,
                              void* d_out, int out_size, void* d_ws, size_t ws_size,
                              hipStream_t stream) {
    const int T = 2048, D = 768, NH = 12, L = 4, V = 32000;
    const int D3 = 3 * D, D4 = 4 * D;

    const int*   idx        = (const int*)d_in[0];
    const float* wte        = (const float*)d_in[1];
    const float* ln1_w      = (const float*)d_in[2];
    const float* attn_w     = (const float*)d_in[3];
    const float* attnproj_w = (const float*)d_in[4];
    const float* ln2_w      = (const float*)d_in[5];
    const float* fc_w       = (const float*)d_in[6];
    const float* fc_b       = (const float*)d_in[7];
    const float* proj_w     = (const float*)d_in[8];
    const float* proj_b     = (const float*)d_in[9];
    const float* lnf_w      = (const float*)d_in[10];
    const float* unemb_b    = (const float*)d_in[11];
    float* out = (float*)d_out;

    // workspace layout (~91.6 MB)
    char* p = (char*)d_ws;
    float*  X      = (float*)p;   p += (size_t)T * D * 4;
    bf16_t* Hb     = (bf16_t*)p;  p += (size_t)T * D * 2;
    float*  QKV    = (float*)p;
    bf16_t* Mb     = (bf16_t*)p;  p += (size_t)T * D3 * 4;
    bf16_t* wte_b  = (bf16_t*)p;  p += (size_t)V * D * 2;
    bf16_t* w_attn = (bf16_t*)p;  p += (size_t)D3 * D * 2;
    bf16_t* w_apr  = (bf16_t*)p;  p += (size_t)D * D * 2;
    bf16_t* w_fc   = (bf16_t*)p;  p += (size_t)D4 * D * 2;
    bf16_t* w_proj = (bf16_t*)p;  p += (size_t)D * D4 * 2;

    // Q/K/V^T bf16 buffers overlay wte_b (dead until after the layer loop)
    bf16_t* Qb  = wte_b;
    bf16_t* Kbf = Qb  + (size_t)NH * T * 64;
    bf16_t* Vtg = Kbf + (size_t)NH * T * 64;

    embed_kernel<<<T, 256, 0, stream>>>(idx, wte, X);

    for (int l = 0; l < L; ++l) {
        int n4;
        n4 = D3 * D / 4;
        cvt_kernel<<<(n4 + 255) / 256, 256, 0, stream>>>(attn_w + (size_t)l * D3 * D, w_attn, n4);
        n4 = D * D / 4;
        cvt_kernel<<<(n4 + 255) / 256, 256, 0, stream>>>(attnproj_w + (size_t)l * D * D, w_apr, n4);
        n4 = D4 * D / 4;
        cvt_kernel<<<(n4 + 255) / 256, 256, 0, stream>>>(fc_w + (size_t)l * D4 * D, w_fc, n4);
        n4 = D * D4 / 4;
        cvt_kernel<<<(n4 + 255) / 256, 256, 0, stream>>>(proj_w + (size_t)l * D * D4, w_proj, n4);

        // h = LN1(x)  (bf16)
        ln_kernel<<<T, 256, 0, stream>>>(X, ln1_w + (size_t)l * D, Hb);
        // qkv = h @ attn_w^T  (fp32 out)
        gemm_bt<0, 128><<<dim3(D3 / 128, T / 128), 256, 0, stream>>>(
            Hb, w_attn, nullptr, QKV, nullptr, T, D3, D);
        // RoPE + bf16 pack + V transpose
        rope_prep<<<dim3(T / 64, NH), 256, 0, stream>>>(QKV, Qb, Kbf, Vtg);
        // y = attn(q,k,v)  (bf16 into Hb)
        attn_mfma<<<dim3(T / 64, NH), 256, 0, stream>>>(Qb, Kbf, Vtg, Hb);
        // x += y @ attnproj_w^T   (BM=64: 192 blocks instead of 96)
        gemm_bt<2, 64><<<dim3(D / 128, T / 64), 256, 0, stream>>>(
            Hb, w_apr, nullptr, X, nullptr, T, D, D);
        // h = LN2(x)
        ln_kernel<<<T, 256, 0, stream>>>(X, ln2_w + (size_t)l * D, Hb);
        // m = gelu(h @ fc_w^T + fc_b)  (bf16 out)
        gemm_bt<13, 128><<<dim3(D4 / 128, T / 128), 256, 0, stream>>>(
            Hb, w_fc, fc_b + (size_t)l * D4, nullptr, Mb, T, D4, D);
        // x += m @ proj_w^T + proj_b   (BM=64)
        gemm_bt<3, 64><<<dim3(D / 128, T / 64), 256, 0, stream>>>(
            Mb, w_proj, proj_b + (size_t)l * D, X, nullptr, T, D, D4);
    }

    // hf = LN(x); logits = hf @ wte^T + unemb_b  (fp32 out)
    ln_kernel<<<T, 256, 0, stream>>>(X, lnf_w, Hb);
    {
        const int n4 = V * D / 4;   // deferred: wte_b region was reused above
        cvt_kernel<<<(n4 + 255) / 256, 256, 0, stream>>>(wte, wte_b, n4);
    }
    // unembed mode: grid x = M tiles (fast axis shares B panel), nt C stores
    gemm_bt<17, 128><<<dim3(T / 128, V / 128), 256, 0, stream>>>(
        Hb, wte_b, unemb_b, out, nullptr, T, V, D);
}